// Round 3
// baseline (392.228 us; speedup 1.0000x reference)
//
#include <hip/hip_runtime.h>

// ---------------------------------------------------------------------------
// MultiheadSparseReluAttention on MI355X (gfx950)
//   q = relu(query @ q_w.T + q_b) * scaling, masked (analytic window mask)
//   k = relu(key   @ k_w.T + k_b),           masked
//   v = value @ v_w.T + v_b
//   attn = per-b Q K^T  (no softmax), out = per-b attn V
// All GEMMs via fp16 MFMA (16x16x32), fp32 accumulate. One shared GEMM
// kernel (m97-style 128x128 tile, BK=32, global_load_lds staging) with
// per-mode epilogues.
// ---------------------------------------------------------------------------

typedef _Float16 f16x8 __attribute__((ext_vector_type(8)));
typedef float f32x4 __attribute__((ext_vector_type(4)));

#define L_DIM 2048
#define B_DIM 4
#define E_DIM 512
#define D_DIM 2048          // NEW_DIM
#define S_DIM 2048
#define SCALING_C 0.02209708691207961f   // 2048^-0.5

// mask window start for row l: row_num=385, zig-zag, step 4, window width 512
__device__ __forceinline__ int win_start(int l) {
    int local = l % 385;
    int blk   = l / 385;
    return ((blk & 1) == 0) ? (local << 2) : ((384 - local) << 2);
}

__device__ __forceinline__ void gload_lds16(const _Float16* g, _Float16* l) {
    __builtin_amdgcn_global_load_lds(
        (const __attribute__((address_space(1))) void*)g,
        (__attribute__((address_space(3))) void*)l, 16, 0, 0);
}

// ---------------------------------------------------------------------------
// fp32 -> fp16 convert, 8 elements / thread
// ---------------------------------------------------------------------------
__global__ void cvt_f32_to_f16(const float* __restrict__ in,
                               _Float16* __restrict__ out, int n8) {
    int i = blockIdx.x * 256 + threadIdx.x;
    if (i >= n8) return;
    const float4* p = (const float4*)in + 2 * (size_t)i;
    float4 a = p[0], b = p[1];
    f16x8 o = {(_Float16)a.x, (_Float16)a.y, (_Float16)a.z, (_Float16)a.w,
               (_Float16)b.x, (_Float16)b.y, (_Float16)b.z, (_Float16)b.w};
    *((f16x8*)out + i) = o;
}

// ---------------------------------------------------------------------------
// V (B,S,E) -> Vt (B,E,S) fp16 transpose, 32x32 LDS tiles
// ---------------------------------------------------------------------------
__global__ void transpose_v(const _Float16* __restrict__ V,
                            _Float16* __restrict__ Vt) {
    __shared__ _Float16 t[32][33];
    int b  = blockIdx.z;
    int s0 = blockIdx.y * 32, e0 = blockIdx.x * 32;
    int tx = threadIdx.x & 31, ty = threadIdx.x >> 5;   // 256 threads
    #pragma unroll
    for (int i = ty; i < 32; i += 8)
        t[i][tx] = V[((size_t)b * S_DIM + s0 + i) * E_DIM + e0 + tx];
    __syncthreads();
    #pragma unroll
    for (int i = ty; i < 32; i += 8)
        Vt[((size_t)b * E_DIM + e0 + i) * S_DIM + s0 + tx] = t[tx][i];
}

// ---------------------------------------------------------------------------
// Shared MFMA GEMM: C[M,N] = A[M,K] * Bm[N,K]^T  (both K-contiguous fp16)
// 128x128 block tile, 4 waves (2x2 of 64x64), BK=32, 16x16x32 f16 MFMA.
// MODE 0: Q proj   -> relu(+bias)*scale, mask, store f16 (B,L,D), row=(l*4+b)
// MODE 1: K proj   -> relu(+bias),       mask, store f16 (B,S,D)
// MODE 2: V proj   -> +bias,                   store f16 (B,S,E)
// MODE 3: attn     -> store f16 (b,L,S), batched over z
// MODE 4: out      -> store f32 (L,B,E), batched over z
// ---------------------------------------------------------------------------
template <int MODE>
__global__ __launch_bounds__(256)
void gemm_mfma(const _Float16* __restrict__ A, const _Float16* __restrict__ Bm,
               const float* __restrict__ bias, void* __restrict__ Cout,
               int K, size_t batchA, size_t batchB) {
    __shared__ __align__(16) _Float16 lA[128 * 32];
    __shared__ __align__(16) _Float16 lB[128 * 32];

    const int tid  = threadIdx.x;
    const int lane = tid & 63;
    const int wid  = tid >> 6;
    const int row0 = blockIdx.y * 128;
    const int col0 = blockIdx.x * 128;
    const int z    = blockIdx.z;

    const _Float16* Ab = A + (size_t)z * batchA + (size_t)row0 * K;
    const _Float16* Bb = Bm + (size_t)z * batchB + (size_t)col0 * K;

    // staging: chunk c covers tile row c>>2, f16 cols (c&3)*8 .. +8
    const int c0 = tid, c1 = tid + 256;
    const _Float16* srcA0 = Ab + (size_t)(c0 >> 2) * K + ((c0 & 3) << 3);
    const _Float16* srcA1 = Ab + (size_t)(c1 >> 2) * K + ((c1 & 3) << 3);
    const _Float16* srcB0 = Bb + (size_t)(c0 >> 2) * K + ((c0 & 3) << 3);
    const _Float16* srcB1 = Bb + (size_t)(c1 >> 2) * K + ((c1 & 3) << 3);
    _Float16* dA0 = &lA[wid * 512];
    _Float16* dA1 = &lA[2048 + wid * 512];
    _Float16* dB0 = &lB[wid * 512];
    _Float16* dB1 = &lB[2048 + wid * 512];

    const int kgrp = (lane >> 4) << 3;                 // 0,8,16,24
    const int arow = (wid >> 1) * 64 + (lane & 15);
    const int brow = (wid & 1) * 64 + (lane & 15);

    f32x4 acc[4][4] = {};

    for (int k0 = 0; k0 < K; k0 += 32) {
        gload_lds16(srcA0, dA0);
        gload_lds16(srcA1, dA1);
        gload_lds16(srcB0, dB0);
        gload_lds16(srcB1, dB1);
        srcA0 += 32; srcA1 += 32; srcB0 += 32; srcB1 += 32;
        asm volatile("s_waitcnt vmcnt(0)" ::: "memory");
        __syncthreads();

        f16x8 af[4], bf[4];
        #pragma unroll
        for (int t = 0; t < 4; ++t) {
            af[t] = *(const f16x8*)&lA[(arow + t * 16) * 32 + kgrp];
            bf[t] = *(const f16x8*)&lB[(brow + t * 16) * 32 + kgrp];
        }
        #pragma unroll
        for (int mt = 0; mt < 4; ++mt)
            #pragma unroll
            for (int nt = 0; nt < 4; ++nt)
                acc[mt][nt] = __builtin_amdgcn_mfma_f32_16x16x32_f16(
                    af[mt], bf[nt], acc[mt][nt], 0, 0, 0);
        __syncthreads();
    }

    // epilogue
    const int colb  = col0 + (wid & 1) * 64 + (lane & 15);
    const int rowb  = row0 + (wid >> 1) * 64 + ((lane >> 4) << 2);
    #pragma unroll
    for (int mt = 0; mt < 4; ++mt) {
        #pragma unroll
        for (int nt = 0; nt < 4; ++nt) {
            f32x4 a = acc[mt][nt];
            int col = colb + nt * 16;
            #pragma unroll
            for (int j = 0; j < 4; ++j) {
                int row = rowb + mt * 16 + j;
                float v = a[j];
                if constexpr (MODE == 0 || MODE == 1) {
                    v += bias[col];
                    v = fmaxf(v, 0.f);
                    if constexpr (MODE == 0) v *= SCALING_C;
                    int l = row >> 2, bb = row & 3;
                    int st = win_start(l);
                    if (col < st || col >= st + 512) v = 0.f;
                    ((_Float16*)Cout)[(((size_t)bb * L_DIM + l) << 11) + col] =
                        (_Float16)v;
                } else if constexpr (MODE == 2) {
                    v += bias[col];
                    int s = row >> 2, bb = row & 3;
                    ((_Float16*)Cout)[(((size_t)bb * S_DIM + s) << 9) + col] =
                        (_Float16)v;
                } else if constexpr (MODE == 3) {
                    ((_Float16*)Cout)[(size_t)z * 4194304 +
                                      ((size_t)row << 11) + col] = (_Float16)v;
                } else {  // MODE 4: out (L,B,E) fp32
                    ((float*)Cout)[(((size_t)row << 2) + z) * 512 + col] = v;
                }
            }
        }
    }
}

// ---------------------------------------------------------------------------
extern "C" void kernel_launch(void* const* d_in, const int* in_sizes, int n_in,
                              void* d_out, int out_size, void* d_ws,
                              size_t ws_size, hipStream_t stream) {
    const float* query = (const float*)d_in[0];
    const float* key_i = (const float*)d_in[1];
    const float* value = (const float*)d_in[2];
    const float* q_w   = (const float*)d_in[3];
    const float* q_b   = (const float*)d_in[4];
    const float* k_w   = (const float*)d_in[5];
    const float* k_b   = (const float*)d_in[6];
    const float* v_w   = (const float*)d_in[7];
    const float* v_b   = (const float*)d_in[8];

    // ws carve (fp16 units)
    _Float16* ws  = (_Float16*)d_ws;
    _Float16* qx  = ws;                    // 8192x512   = 4,194,304
    _Float16* kx  = qx + 4194304;
    _Float16* vx  = kx + 4194304;
    _Float16* qwf = vx + 4194304;          // 2048x512   = 1,048,576
    _Float16* kwf = qwf + 1048576;
    _Float16* vwf = kwf + 1048576;         // 512x512    =   262,144
    _Float16* Qb  = vwf + 262144;          // (B,L,D)    = 16,777,216
    _Float16* Kb  = Qb + 16777216;         // (B,S,D)
    _Float16* Vb  = Kb + 16777216;         // (B,S,E)    =  4,194,304
    _Float16* Vt  = Vb + 4194304;          // (B,E,S)
    _Float16* At  = Vt + 4194304;          // (B,L,S)    = 16,777,216

    // 1) convert inputs + weights to fp16
    cvt_f32_to_f16<<<2048, 256, 0, stream>>>(query, qx, 524288);
    cvt_f32_to_f16<<<2048, 256, 0, stream>>>(key_i, kx, 524288);
    cvt_f32_to_f16<<<2048, 256, 0, stream>>>(value, vx, 524288);
    cvt_f32_to_f16<<<512,  256, 0, stream>>>(q_w, qwf, 131072);
    cvt_f32_to_f16<<<512,  256, 0, stream>>>(k_w, kwf, 131072);
    cvt_f32_to_f16<<<128,  256, 0, stream>>>(v_w, vwf, 32768);

    // 2) projections
    gemm_mfma<0><<<dim3(16, 64, 1), 256, 0, stream>>>(qx, qwf, q_b, Qb, 512, 0, 0);
    gemm_mfma<1><<<dim3(16, 64, 1), 256, 0, stream>>>(kx, kwf, k_b, Kb, 512, 0, 0);
    gemm_mfma<2><<<dim3(4, 64, 1), 256, 0, stream>>>(vx, vwf, v_b, Vb, 512, 0, 0);

    // 3) V -> V^T
    transpose_v<<<dim3(16, 64, 4), 256, 0, stream>>>(Vb, Vt);

    // 4) attn = Q K^T (batched over b)
    gemm_mfma<3><<<dim3(16, 16, 4), 256, 0, stream>>>(Qb, Kb, nullptr, At, 2048,
                                                      4194304, 4194304);

    // 5) out = attn V  (B-operand = Vt rows e)
    gemm_mfma<4><<<dim3(4, 16, 4), 256, 0, stream>>>(At, Vt, nullptr, d_out,
                                                     2048, 4194304, 1048576);
}

// Round 4
// 325.453 us; speedup vs baseline: 1.2052x; 1.2052x over previous
//
#include <hip/hip_runtime.h>

// ---------------------------------------------------------------------------
// MultiheadSparseReluAttention on MI355X (gfx950)
// Round 4: 256x256 8-wave 4-subphase MFMA GEMM (T1 XCD-swizzle, T2 LDS
// XOR-swizzle, T3/T4 phase pipeline w/ counted drains, T5 setprio) for the
// three big GEMMs (Q proj, K proj, attn). 128^2 kernel kept for V proj + out.
// ---------------------------------------------------------------------------

typedef _Float16 f16x8 __attribute__((ext_vector_type(8)));
typedef float f32x4 __attribute__((ext_vector_type(4)));

#define L_DIM 2048
#define E_DIM 512
#define S_DIM 2048
#define SCALING_C 0.02209708691207961f   // 2048^-0.5

__device__ __forceinline__ int win_start(int l) {
    int local = l % 385;
    int blk   = l / 385;
    return ((blk & 1) == 0) ? (local << 2) : ((384 - local) << 2);
}

__device__ __forceinline__ void gload_lds16(const _Float16* g, _Float16* l) {
    __builtin_amdgcn_global_load_lds(
        (const __attribute__((address_space(1))) void*)g,
        (__attribute__((address_space(3))) void*)l, 16, 0, 0);
}

// ---------------------------------------------------------------------------
__global__ void cvt_f32_to_f16(const float* __restrict__ in,
                               _Float16* __restrict__ out, int n8) {
    int i = blockIdx.x * 256 + threadIdx.x;
    if (i >= n8) return;
    const float4* p = (const float4*)in + 2 * (size_t)i;
    float4 a = p[0], b = p[1];
    f16x8 o = {(_Float16)a.x, (_Float16)a.y, (_Float16)a.z, (_Float16)a.w,
               (_Float16)b.x, (_Float16)b.y, (_Float16)b.z, (_Float16)b.w};
    *((f16x8*)out + i) = o;
}

// ---------------------------------------------------------------------------
__global__ void transpose_v(const _Float16* __restrict__ V,
                            _Float16* __restrict__ Vt) {
    __shared__ _Float16 t[32][33];
    int b  = blockIdx.z;
    int s0 = blockIdx.y * 32, e0 = blockIdx.x * 32;
    int tx = threadIdx.x & 31, ty = threadIdx.x >> 5;
    #pragma unroll
    for (int i = ty; i < 32; i += 8)
        t[i][tx] = V[((size_t)b * S_DIM + s0 + i) * E_DIM + e0 + tx];
    __syncthreads();
    #pragma unroll
    for (int i = ty; i < 32; i += 8)
        Vt[((size_t)b * E_DIM + e0 + i) * S_DIM + s0 + tx] = t[tx][i];
}

// ---------------------------------------------------------------------------
// 128x128 tile kernel (kept for MODE 2: V proj, MODE 4: out GEMM)
// ---------------------------------------------------------------------------
template <int MODE>
__global__ __launch_bounds__(256)
void gemm_mfma(const _Float16* __restrict__ A, const _Float16* __restrict__ Bm,
               const float* __restrict__ bias, void* __restrict__ Cout,
               int K, size_t batchA, size_t batchB) {
    __shared__ __align__(16) _Float16 lA[128 * 32];
    __shared__ __align__(16) _Float16 lB[128 * 32];

    const int tid  = threadIdx.x;
    const int lane = tid & 63;
    const int wid  = tid >> 6;
    const int row0 = blockIdx.y * 128;
    const int col0 = blockIdx.x * 128;
    const int z    = blockIdx.z;

    const _Float16* Ab = A + (size_t)z * batchA + (size_t)row0 * K;
    const _Float16* Bb = Bm + (size_t)z * batchB + (size_t)col0 * K;

    const int c0 = tid, c1 = tid + 256;
    const _Float16* srcA0 = Ab + (size_t)(c0 >> 2) * K + ((c0 & 3) << 3);
    const _Float16* srcA1 = Ab + (size_t)(c1 >> 2) * K + ((c1 & 3) << 3);
    const _Float16* srcB0 = Bb + (size_t)(c0 >> 2) * K + ((c0 & 3) << 3);
    const _Float16* srcB1 = Bb + (size_t)(c1 >> 2) * K + ((c1 & 3) << 3);
    _Float16* dA0 = &lA[wid * 512];
    _Float16* dA1 = &lA[2048 + wid * 512];
    _Float16* dB0 = &lB[wid * 512];
    _Float16* dB1 = &lB[2048 + wid * 512];

    const int kgrp = (lane >> 4) << 3;
    const int arow = (wid >> 1) * 64 + (lane & 15);
    const int brow = (wid & 1) * 64 + (lane & 15);

    f32x4 acc[4][4] = {};

    for (int k0 = 0; k0 < K; k0 += 32) {
        gload_lds16(srcA0, dA0);
        gload_lds16(srcA1, dA1);
        gload_lds16(srcB0, dB0);
        gload_lds16(srcB1, dB1);
        srcA0 += 32; srcA1 += 32; srcB0 += 32; srcB1 += 32;
        asm volatile("s_waitcnt vmcnt(0)" ::: "memory");
        __syncthreads();

        f16x8 af[4], bf[4];
        #pragma unroll
        for (int t = 0; t < 4; ++t) {
            af[t] = *(const f16x8*)&lA[(arow + t * 16) * 32 + kgrp];
            bf[t] = *(const f16x8*)&lB[(brow + t * 16) * 32 + kgrp];
        }
        #pragma unroll
        for (int mt = 0; mt < 4; ++mt)
            #pragma unroll
            for (int nt = 0; nt < 4; ++nt)
                acc[mt][nt] = __builtin_amdgcn_mfma_f32_16x16x32_f16(
                    af[mt], bf[nt], acc[mt][nt], 0, 0, 0);
        __syncthreads();
    }

    const int colb  = col0 + (wid & 1) * 64 + (lane & 15);
    const int rowb  = row0 + (wid >> 1) * 64 + ((lane >> 4) << 2);
    #pragma unroll
    for (int mt = 0; mt < 4; ++mt) {
        #pragma unroll
        for (int nt = 0; nt < 4; ++nt) {
            f32x4 a = acc[mt][nt];
            int col = colb + nt * 16;
            #pragma unroll
            for (int j = 0; j < 4; ++j) {
                int row = rowb + mt * 16 + j;
                float v = a[j];
                if constexpr (MODE == 2) {
                    v += bias[col];
                    int s = row >> 2, bb = row & 3;
                    ((_Float16*)Cout)[(((size_t)bb * S_DIM + s) << 9) + col] =
                        (_Float16)v;
                } else {  // MODE 4: out (L,B,E) fp32
                    ((float*)Cout)[(((size_t)row << 2) + z) * 512 + col] = v;
                }
            }
        }
    }
}

// ---------------------------------------------------------------------------
// 256x256 tile, BK=64, 512 threads (8 waves, 2Mx4N), double-buffered LDS
// (128 KiB), 4 subphases per K-tile, LDS XOR-swizzle (byte ^= (row&7)<<4)
// applied via inverse-swizzled global source + swizzled ds_read (rule 21),
// raw s_barrier + one counted vmcnt(0) per K-tile, setprio around MFMA.
// MODE 0: Q proj  MODE 1: K proj  MODE 3: attn
// ---------------------------------------------------------------------------
#define STAGE_H(b_, mat_, h_, j_) \
    gload_lds16(src[mat_][h_][j_], \
                &sm[b_][mat_][(h_) * 8192 + wid * 1024 + (j_) * 512])
#define ADV() do { \
    src[0][0][0] += 64; src[0][0][1] += 64; src[0][1][0] += 64; src[0][1][1] += 64; \
    src[1][0][0] += 64; src[1][0][1] += 64; src[1][1][0] += 64; src[1][1][1] += 64; \
} while (0)

template <int MODE>
__global__ __launch_bounds__(512, 2)
void gemm256(const _Float16* __restrict__ A, const _Float16* __restrict__ Bm,
             const float* __restrict__ bias, void* __restrict__ Cout,
             int K, size_t batchA, size_t batchB, int nbx, int nby) {
    __shared__ __align__(16) _Float16 sm[2][2][16384];   // [buf][A/B][256*64]

    // T1: bijective XCD swizzle (gridDim.x % 8 == 0 by construction)
    const int nwg  = gridDim.x;
    const int orig = blockIdx.x;
    const int swz  = (orig & 7) * (nwg >> 3) + (orig >> 3);
    const int bx   = swz % nbx;
    const int rem  = swz / nbx;
    const int by   = rem % nby;
    const int z    = rem / nby;

    const int tid  = threadIdx.x;
    const int lane = tid & 63;
    const int wid  = tid >> 6;
    const int wr   = wid >> 2;          // 0..1  (M half)
    const int wc   = wid & 3;           // 0..3  (N quarter)
    const int row0 = by << 8, col0 = bx << 8;

    const _Float16* Ab = A + (size_t)z * batchA + (size_t)row0 * K;
    const _Float16* Bb = Bm + (size_t)z * batchB + (size_t)col0 * K;

    // staging sources: chunk c = wid*128 + j*64 + lane covers LDS bytes c*16
    // (linear dest); logical (row r = c>>3, slot = c&7 = lane&7) holds global
    // col16 = (lane&7) ^ (r&7)  (inverse of read-side swizzle).
    const _Float16* src[2][2][2];       // [mat][half][j]
    #pragma unroll
    for (int h = 0; h < 2; ++h)
        #pragma unroll
        for (int j = 0; j < 2; ++j) {
            const int c  = wid * 128 + j * 64 + lane;
            const int r  = c >> 3;
            const int sc = ((lane & 7) ^ (r & 7)) << 3;
            src[0][h][j] = Ab + (size_t)(h * 128 + r) * K + sc;
            src[1][h][j] = Bb + (size_t)(h * 128 + r) * K + sc;
        }

    // prologue: stage tile 0 -> buf 0
    STAGE_H(0, 0, 0, 0); STAGE_H(0, 0, 0, 1); STAGE_H(0, 0, 1, 0); STAGE_H(0, 0, 1, 1);
    STAGE_H(0, 1, 0, 0); STAGE_H(0, 1, 0, 1); STAGE_H(0, 1, 1, 0); STAGE_H(0, 1, 1, 1);
    ADV();
    asm volatile("s_waitcnt vmcnt(0)" ::: "memory");
    __builtin_amdgcn_s_barrier();

    f32x4 acc[8][4] = {};
    const int q4   = lane >> 4;
    const int sl0  = ((q4 ^ (lane & 7)) << 4);          // kk=0 swizzled slot
    const int sl1  = (((4 + q4) ^ (lane & 7)) << 4);    // kk=1
    const int aoff = (wr * 128 + (lane & 15)) * 128;    // byte row base, A
    const int boff = (wc * 64 + (lane & 15)) * 128;     // byte row base, B
    const int NT   = K >> 6;

    for (int t = 0; t < NT; ++t) {
        const int  cur = t & 1, nxt = cur ^ 1;
        const bool pre = (t + 1 < NT);
        const char* bA = (const char*)&sm[cur][0][0];
        const char* bB = (const char*)&sm[cur][1][0];

        f16x8 bf[4][2];
        #pragma unroll
        for (int p = 0; p < 4; ++p) {
            if (p == 0) {
                #pragma unroll
                for (int n = 0; n < 4; ++n) {
                    bf[n][0] = *(const f16x8*)(bB + boff + n * 2048 + sl0);
                    bf[n][1] = *(const f16x8*)(bB + boff + n * 2048 + sl1);
                }
            }
            f16x8 a00 = *(const f16x8*)(bA + aoff + (2 * p) * 2048 + sl0);
            f16x8 a01 = *(const f16x8*)(bA + aoff + (2 * p) * 2048 + sl1);
            f16x8 a10 = *(const f16x8*)(bA + aoff + (2 * p + 1) * 2048 + sl0);
            f16x8 a11 = *(const f16x8*)(bA + aoff + (2 * p + 1) * 2048 + sl1);
            if (pre) {
                if (p == 0) { STAGE_H(nxt, 0, 0, 0); STAGE_H(nxt, 0, 0, 1);
                              STAGE_H(nxt, 0, 1, 0); STAGE_H(nxt, 0, 1, 1); }
                if (p == 1) { STAGE_H(nxt, 1, 0, 0); STAGE_H(nxt, 1, 0, 1);
                              STAGE_H(nxt, 1, 1, 0); STAGE_H(nxt, 1, 1, 1); ADV(); }
            }
            __builtin_amdgcn_s_barrier();
            __builtin_amdgcn_s_setprio(1);
            #pragma unroll
            for (int i = 0; i < 2; ++i) {
                f16x8 a0 = (i == 0) ? a00 : a10;
                f16x8 a1 = (i == 0) ? a01 : a11;
                #pragma unroll
                for (int n = 0; n < 4; ++n) {
                    acc[2 * p + i][n] = __builtin_amdgcn_mfma_f32_16x16x32_f16(
                        a0, bf[n][0], acc[2 * p + i][n], 0, 0, 0);
                    acc[2 * p + i][n] = __builtin_amdgcn_mfma_f32_16x16x32_f16(
                        a1, bf[n][1], acc[2 * p + i][n], 0, 0, 0);
                }
            }
            __builtin_amdgcn_s_setprio(0);
            if (p == 3 && pre) asm volatile("s_waitcnt vmcnt(0)" ::: "memory");
            __builtin_amdgcn_s_barrier();
        }
    }

    // epilogue: C/D layout col=lane&15, row=q4*4+jj
    const int colg = col0 + wc * 64 + (lane & 15);
    const int rowg = row0 + wr * 128 + q4 * 4;
    float bv[4];
    if constexpr (MODE == 0 || MODE == 1) {
        #pragma unroll
        for (int n = 0; n < 4; ++n) bv[n] = bias[colg + n * 16];
    }
    #pragma unroll
    for (int m = 0; m < 8; ++m) {
        #pragma unroll
        for (int n = 0; n < 4; ++n) {
            const int col = colg + n * 16;
            #pragma unroll
            for (int jj = 0; jj < 4; ++jj) {
                const int row = rowg + m * 16 + jj;
                float v = acc[m][n][jj];
                if constexpr (MODE == 0 || MODE == 1) {
                    v = fmaxf(v + bv[n], 0.f);
                    if constexpr (MODE == 0) v *= SCALING_C;
                    const int l = row >> 2, bb = row & 3;
                    const int st = win_start(l);
                    if (col < st || col >= st + 512) v = 0.f;
                    ((_Float16*)Cout)[(((size_t)bb * L_DIM + l) << 11) + col] =
                        (_Float16)v;
                } else {  // MODE 3: attn f16 (b, L, S)
                    ((_Float16*)Cout)[(size_t)z * 4194304 +
                                      ((size_t)row << 11) + col] = (_Float16)v;
                }
            }
        }
    }
}

// ---------------------------------------------------------------------------
extern "C" void kernel_launch(void* const* d_in, const int* in_sizes, int n_in,
                              void* d_out, int out_size, void* d_ws,
                              size_t ws_size, hipStream_t stream) {
    const float* query = (const float*)d_in[0];
    const float* key_i = (const float*)d_in[1];
    const float* value = (const float*)d_in[2];
    const float* q_w   = (const float*)d_in[3];
    const float* q_b   = (const float*)d_in[4];
    const float* k_w   = (const float*)d_in[5];
    const float* k_b   = (const float*)d_in[6];
    const float* v_w   = (const float*)d_in[7];
    const float* v_b   = (const float*)d_in[8];

    _Float16* ws  = (_Float16*)d_ws;
    _Float16* qx  = ws;                    // 8192x512
    _Float16* kx  = qx + 4194304;
    _Float16* vx  = kx + 4194304;
    _Float16* qwf = vx + 4194304;          // 2048x512
    _Float16* kwf = qwf + 1048576;
    _Float16* vwf = kwf + 1048576;         // 512x512
    _Float16* Qb  = vwf + 262144;          // (B,L,D)
    _Float16* Kb  = Qb + 16777216;         // (B,S,D)
    _Float16* Vb  = Kb + 16777216;         // (B,S,E)
    _Float16* Vt  = Vb + 4194304;          // (B,E,S)
    _Float16* At  = Vt + 4194304;          // (B,L,S)

    cvt_f32_to_f16<<<2048, 256, 0, stream>>>(query, qx, 524288);
    cvt_f32_to_f16<<<2048, 256, 0, stream>>>(key_i, kx, 524288);
    cvt_f32_to_f16<<<2048, 256, 0, stream>>>(value, vx, 524288);
    cvt_f32_to_f16<<<512,  256, 0, stream>>>(q_w, qwf, 131072);
    cvt_f32_to_f16<<<512,  256, 0, stream>>>(k_w, kwf, 131072);
    cvt_f32_to_f16<<<128,  256, 0, stream>>>(v_w, vwf, 32768);

    // projections: Q/K on 256^2 pipeline kernel, V on 128^2
    gemm256<0><<<dim3(256), 512, 0, stream>>>(qx, qwf, q_b, Qb, 512, 0, 0, 8, 32);
    gemm256<1><<<dim3(256), 512, 0, stream>>>(kx, kwf, k_b, Kb, 512, 0, 0, 8, 32);
    gemm_mfma<2><<<dim3(4, 64, 1), 256, 0, stream>>>(vx, vwf, v_b, Vb, 512, 0, 0);

    transpose_v<<<dim3(16, 64, 4), 256, 0, stream>>>(Vb, Vt);

    // attn = Q K^T (batched over b)
    gemm256<3><<<dim3(256), 512, 0, stream>>>(Qb, Kb, nullptr, At, 2048,
                                              4194304, 4194304, 8, 8);

    // out = attn V
    gemm_mfma<4><<<dim3(4, 16, 4), 256, 0, stream>>>(At, Vt, nullptr, d_out,
                                                     2048, 4194304, 1048576);
}

// Round 9
// 277.671 us; speedup vs baseline: 1.4126x; 1.1721x over previous
//
#include <hip/hip_runtime.h>

// ---------------------------------------------------------------------------
// MultiheadSparseReluAttention on MI355X (gfx950)
// Round 5 (4th resubmit; broker timeouts): single-barrier-per-K-tile
// pipelined schedule (LDS reads overlap MFMA), 256^2 kernel for Q/K proj +
// attn, 128^2 pipelined kernel for V proj + out GEMM. Merged cvt launches.
// ---------------------------------------------------------------------------

typedef _Float16 f16x8 __attribute__((ext_vector_type(8)));
typedef float f32x4 __attribute__((ext_vector_type(4)));

#define L_DIM 2048
#define E_DIM 512
#define S_DIM 2048
#define SCALING_C 0.02209708691207961f   // 2048^-0.5

__device__ __forceinline__ int win_start(int l) {
    int local = l % 385;
    int blk   = l / 385;
    return ((blk & 1) == 0) ? (local << 2) : ((384 - local) << 2);
}

__device__ __forceinline__ void gload_lds16(const _Float16* g, _Float16* l) {
    __builtin_amdgcn_global_load_lds(
        (const __attribute__((address_space(1))) void*)g,
        (__attribute__((address_space(3))) void*)l, 16, 0, 0);
}

// ---------------------------------------------------------------------------
// merged fp32 -> fp16 converts (y selects tensor)
// ---------------------------------------------------------------------------
__global__ void cvt3(const float* __restrict__ p0, const float* __restrict__ p1,
                     const float* __restrict__ p2, _Float16* __restrict__ o0,
                     _Float16* __restrict__ o1, _Float16* __restrict__ o2,
                     int n0, int n1, int n2) {
    const int y = blockIdx.y;
    const float* in  = (y == 0) ? p0 : (y == 1) ? p1 : p2;
    _Float16*    out = (y == 0) ? o0 : (y == 1) ? o1 : o2;
    const int    n8  = (y == 0) ? n0 : (y == 1) ? n1 : n2;
    int i = blockIdx.x * 256 + threadIdx.x;
    if (i >= n8) return;
    const float4* p = (const float4*)in + 2 * (size_t)i;
    float4 a = p[0], b = p[1];
    f16x8 o = {(_Float16)a.x, (_Float16)a.y, (_Float16)a.z, (_Float16)a.w,
               (_Float16)b.x, (_Float16)b.y, (_Float16)b.z, (_Float16)b.w};
    *((f16x8*)out + i) = o;
}

// ---------------------------------------------------------------------------
__global__ void transpose_v(const _Float16* __restrict__ V,
                            _Float16* __restrict__ Vt) {
    __shared__ _Float16 t[32][33];
    int b  = blockIdx.z;
    int s0 = blockIdx.y * 32, e0 = blockIdx.x * 32;
    int tx = threadIdx.x & 31, ty = threadIdx.x >> 5;
    #pragma unroll
    for (int i = ty; i < 32; i += 8)
        t[i][tx] = V[((size_t)b * S_DIM + s0 + i) * E_DIM + e0 + tx];
    __syncthreads();
    #pragma unroll
    for (int i = ty; i < 32; i += 8)
        Vt[((size_t)b * E_DIM + e0 + i) * S_DIM + s0 + tx] = t[tx][i];
}

// ===========================================================================
// 256x256 tile, BK=64, 512 threads (8 waves 2Mx4N), dbuf LDS 128KB.
// ONE s_barrier + one vmcnt(0) per K-tile; A-frag ds_reads pipelined one
// phase ahead of the MFMA cluster so LDS and MFMA pipes overlap.
// MODE 0: Q proj  MODE 1: K proj  MODE 3: attn
// ===========================================================================
#define STAGE256(b_, mat_, h_, j_) \
    gload_lds16(srcb[mat_] + (size_t)((h_) * 128 + (j_) * 8) * K, \
                &sm[b_][mat_][(h_) * 8192 + wid * 1024 + (j_) * 512])

template <int MODE>
__global__ __launch_bounds__(512, 2)
void gemm256(const _Float16* __restrict__ A, const _Float16* __restrict__ Bm,
             const float* __restrict__ bias, void* __restrict__ Cout,
             int K, size_t batchA, size_t batchB, int nbx, int nby) {
    __shared__ __align__(16) _Float16 sm[2][2][16384];   // [buf][A/B][256*64]

    // T1: bijective XCD swizzle (gridDim.x % 8 == 0)
    const int nwg  = gridDim.x;
    const int orig = blockIdx.x;
    const int swz  = (orig & 7) * (nwg >> 3) + (orig >> 3);
    const int bx   = swz % nbx;
    const int rem  = swz / nbx;
    const int by   = rem % nby;
    const int z    = rem / nby;

    const int tid  = threadIdx.x;
    const int lane = tid & 63;
    const int wid  = tid >> 6;
    const int wr   = wid >> 2;          // M half
    const int wc   = wid & 3;           // N quarter
    const int row0 = by << 8, col0 = bx << 8;

    const _Float16* Ab = A + (size_t)z * batchA + (size_t)row0 * K;
    const _Float16* Bb = Bm + (size_t)z * batchB + (size_t)col0 * K;

    // staging base (per-lane): row r = wid*16 + (lane>>3) (+h*128 + j*8),
    // swizzled col16 = (lane&7) ^ (lane>>3)   [r&7 == lane>>3 for all h,j]
    const int rl = wid * 16 + (lane >> 3);
    const int sc = ((lane & 7) ^ (lane >> 3)) << 3;
    const _Float16* srcb[2] = { Ab + (size_t)rl * K + sc,
                                Bb + (size_t)rl * K + sc };

    // prologue: stage tile 0 -> buf 0
    STAGE256(0, 0, 0, 0); STAGE256(0, 0, 0, 1); STAGE256(0, 0, 1, 0); STAGE256(0, 0, 1, 1);
    STAGE256(0, 1, 0, 0); STAGE256(0, 1, 0, 1); STAGE256(0, 1, 1, 0); STAGE256(0, 1, 1, 1);
    srcb[0] += 64; srcb[1] += 64;
    asm volatile("s_waitcnt vmcnt(0)" ::: "memory");
    __builtin_amdgcn_s_barrier();

    f32x4 acc[8][4] = {};
    const int q4   = lane >> 4;
    const int sl0  = ((q4 ^ (lane & 7)) << 4);        // kk=0 swizzled slot
    const int sl1  = (((4 + q4) ^ (lane & 7)) << 4);  // kk=1
    const int aoff = (wr * 128 + (lane & 15)) * 128;  // byte base, A rows
    const int boff = (wc * 64 + (lane & 15)) * 128;   // byte base, B rows
    const int NT   = K >> 6;

    for (int t = 0; t < NT; ++t) {
        const int  cur = t & 1, nxt = cur ^ 1;
        const bool pre = (t + 1 < NT);
        const char* bA = (const char*)&sm[cur][0][0];
        const char* bB = (const char*)&sm[cur][1][0];

        f16x8 bf[4][2], a[2][4];
        #pragma unroll
        for (int n = 0; n < 4; ++n) {
            bf[n][0] = *(const f16x8*)(bB + boff + n * 2048 + sl0);
            bf[n][1] = *(const f16x8*)(bB + boff + n * 2048 + sl1);
        }
        a[0][0] = *(const f16x8*)(bA + aoff + 0 * 2048 + sl0);
        a[0][1] = *(const f16x8*)(bA + aoff + 0 * 2048 + sl1);
        a[0][2] = *(const f16x8*)(bA + aoff + 1 * 2048 + sl0);
        a[0][3] = *(const f16x8*)(bA + aoff + 1 * 2048 + sl1);
        if (pre) { STAGE256(nxt, 0, 0, 0); STAGE256(nxt, 0, 0, 1);
                   STAGE256(nxt, 0, 1, 0); STAGE256(nxt, 0, 1, 1); }

        #pragma unroll
        for (int p = 0; p < 4; ++p) {
            if (p < 3) {   // pipeline next phase's A-frags ahead of MFMA
                a[(p + 1) & 1][0] = *(const f16x8*)(bA + aoff + (2 * p + 2) * 2048 + sl0);
                a[(p + 1) & 1][1] = *(const f16x8*)(bA + aoff + (2 * p + 2) * 2048 + sl1);
                a[(p + 1) & 1][2] = *(const f16x8*)(bA + aoff + (2 * p + 3) * 2048 + sl0);
                a[(p + 1) & 1][3] = *(const f16x8*)(bA + aoff + (2 * p + 3) * 2048 + sl1);
            }
            if (p == 0 && pre) {
                STAGE256(nxt, 1, 0, 0); STAGE256(nxt, 1, 0, 1);
                STAGE256(nxt, 1, 1, 0); STAGE256(nxt, 1, 1, 1);
                srcb[0] += 64; srcb[1] += 64;
            }
            __builtin_amdgcn_s_setprio(1);
            #pragma unroll
            for (int i = 0; i < 2; ++i) {
                #pragma unroll
                for (int n = 0; n < 4; ++n) {
                    acc[2 * p + i][n] = __builtin_amdgcn_mfma_f32_16x16x32_f16(
                        a[p & 1][2 * i], bf[n][0], acc[2 * p + i][n], 0, 0, 0);
                    acc[2 * p + i][n] = __builtin_amdgcn_mfma_f32_16x16x32_f16(
                        a[p & 1][2 * i + 1], bf[n][1], acc[2 * p + i][n], 0, 0, 0);
                }
            }
            __builtin_amdgcn_s_setprio(0);
        }
        // buffer-recycle protection: own gloads drained, then all waves sync
        asm volatile("s_waitcnt vmcnt(0)" ::: "memory");
        __builtin_amdgcn_s_barrier();
    }

    // epilogue: C/D layout col=lane&15, row=q4*4+jj
    const int colg = col0 + wc * 64 + (lane & 15);
    const int rowg = row0 + wr * 128 + q4 * 4;
    float bv[4];
    if constexpr (MODE == 0 || MODE == 1) {
        #pragma unroll
        for (int n = 0; n < 4; ++n) bv[n] = bias[colg + n * 16];
    }
    #pragma unroll
    for (int m = 0; m < 8; ++m) {
        #pragma unroll
        for (int n = 0; n < 4; ++n) {
            const int col = colg + n * 16;
            #pragma unroll
            for (int jj = 0; jj < 4; ++jj) {
                const int row = rowg + m * 16 + jj;
                float v = acc[m][n][jj];
                if constexpr (MODE == 0 || MODE == 1) {
                    v = fmaxf(v + bv[n], 0.f);
                    if constexpr (MODE == 0) v *= SCALING_C;
                    const int l = row >> 2, bb = row & 3;
                    const int st = win_start(l);
                    if (col < st || col >= st + 512) v = 0.f;
                    ((_Float16*)Cout)[(((size_t)bb * L_DIM + l) << 11) + col] =
                        (_Float16)v;
                } else {  // MODE 3: attn f16 (b, L, S)
                    ((_Float16*)Cout)[(size_t)z * 4194304 +
                                      ((size_t)row << 11) + col] = (_Float16)v;
                }
            }
        }
    }
}

// ===========================================================================
// 128x128 tile, BK=64, 256 threads (4 waves 2x2), dbuf LDS 64KB (2 blk/CU).
// Same pipelined single-barrier schedule. MODE 2: V proj  MODE 4: out GEMM
// ===========================================================================
#define STAGE128(b_, mat_, j_) \
    gload_lds16(srcb[mat_] + (size_t)((j_) * 32) * K, \
                &sm[b_][mat_][(j_) * 2048 + wid * 512])

template <int MODE>
__global__ __launch_bounds__(256, 2)
void gemm128p(const _Float16* __restrict__ A, const _Float16* __restrict__ Bm,
              const float* __restrict__ bias, void* __restrict__ Cout,
              int K, size_t batchA, size_t batchB, int nbx, int nby) {
    __shared__ __align__(16) _Float16 sm[2][2][8192];    // [buf][A/B][128*64]

    const int nwg  = gridDim.x;
    const int orig = blockIdx.x;
    const int swz  = (orig & 7) * (nwg >> 3) + (orig >> 3);
    const int bx   = swz % nbx;
    const int rem  = swz / nbx;
    const int by   = rem % nby;
    const int z    = rem / nby;

    const int tid  = threadIdx.x;
    const int lane = tid & 63;
    const int wid  = tid >> 6;
    const int wr   = wid >> 1;
    const int wc   = wid & 1;
    const int row0 = by << 7, col0 = bx << 7;

    const _Float16* Ab = A + (size_t)z * batchA + (size_t)row0 * K;
    const _Float16* Bb = Bm + (size_t)z * batchB + (size_t)col0 * K;

    const int rl = wid * 8 + (lane >> 3);
    const int sc = ((lane & 7) ^ (lane >> 3)) << 3;
    const _Float16* srcb[2] = { Ab + (size_t)rl * K + sc,
                                Bb + (size_t)rl * K + sc };

    STAGE128(0, 0, 0); STAGE128(0, 0, 1); STAGE128(0, 0, 2); STAGE128(0, 0, 3);
    STAGE128(0, 1, 0); STAGE128(0, 1, 1); STAGE128(0, 1, 2); STAGE128(0, 1, 3);
    srcb[0] += 64; srcb[1] += 64;
    asm volatile("s_waitcnt vmcnt(0)" ::: "memory");
    __builtin_amdgcn_s_barrier();

    f32x4 acc[4][4] = {};
    const int q4   = lane >> 4;
    const int sl0  = ((q4 ^ (lane & 7)) << 4);
    const int sl1  = (((4 + q4) ^ (lane & 7)) << 4);
    const int aoff = (wr * 64 + (lane & 15)) * 128;
    const int boff = (wc * 64 + (lane & 15)) * 128;
    const int NT   = K >> 6;

    for (int t = 0; t < NT; ++t) {
        const int  cur = t & 1, nxt = cur ^ 1;
        const bool pre = (t + 1 < NT);
        const char* bA = (const char*)&sm[cur][0][0];
        const char* bB = (const char*)&sm[cur][1][0];

        f16x8 bf[4][2], a[2][4];
        #pragma unroll
        for (int n = 0; n < 4; ++n) {
            bf[n][0] = *(const f16x8*)(bB + boff + n * 2048 + sl0);
            bf[n][1] = *(const f16x8*)(bB + boff + n * 2048 + sl1);
        }
        a[0][0] = *(const f16x8*)(bA + aoff + 0 * 2048 + sl0);
        a[0][1] = *(const f16x8*)(bA + aoff + 0 * 2048 + sl1);
        a[0][2] = *(const f16x8*)(bA + aoff + 1 * 2048 + sl0);
        a[0][3] = *(const f16x8*)(bA + aoff + 1 * 2048 + sl1);
        if (pre) { STAGE128(nxt, 0, 0); STAGE128(nxt, 0, 1);
                   STAGE128(nxt, 0, 2); STAGE128(nxt, 0, 3); }

        #pragma unroll
        for (int p = 0; p < 2; ++p) {
            if (p < 1) {
                a[1][0] = *(const f16x8*)(bA + aoff + 2 * 2048 + sl0);
                a[1][1] = *(const f16x8*)(bA + aoff + 2 * 2048 + sl1);
                a[1][2] = *(const f16x8*)(bA + aoff + 3 * 2048 + sl0);
                a[1][3] = *(const f16x8*)(bA + aoff + 3 * 2048 + sl1);
            }
            if (p == 0 && pre) {
                STAGE128(nxt, 1, 0); STAGE128(nxt, 1, 1);
                STAGE128(nxt, 1, 2); STAGE128(nxt, 1, 3);
                srcb[0] += 64; srcb[1] += 64;
            }
            __builtin_amdgcn_s_setprio(1);
            #pragma unroll
            for (int i = 0; i < 2; ++i) {
                #pragma unroll
                for (int n = 0; n < 4; ++n) {
                    acc[2 * p + i][n] = __builtin_amdgcn_mfma_f32_16x16x32_f16(
                        a[p][2 * i], bf[n][0], acc[2 * p + i][n], 0, 0, 0);
                    acc[2 * p + i][n] = __builtin_amdgcn_mfma_f32_16x16x32_f16(
                        a[p][2 * i + 1], bf[n][1], acc[2 * p + i][n], 0, 0, 0);
                }
            }
            __builtin_amdgcn_s_setprio(0);
        }
        asm volatile("s_waitcnt vmcnt(0)" ::: "memory");
        __builtin_amdgcn_s_barrier();
    }

    const int colg = col0 + wc * 64 + (lane & 15);
    const int rowg = row0 + wr * 64 + q4 * 4;
    #pragma unroll
    for (int m = 0; m < 4; ++m) {
        #pragma unroll
        for (int n = 0; n < 4; ++n) {
            const int col = colg + n * 16;
            #pragma unroll
            for (int jj = 0; jj < 4; ++jj) {
                const int row = rowg + m * 16 + jj;
                float v = acc[m][n][jj];
                if constexpr (MODE == 2) {
                    v += bias[col];
                    const int s = row >> 2, bb = row & 3;
                    ((_Float16*)Cout)[(((size_t)bb * S_DIM + s) << 9) + col] =
                        (_Float16)v;
                } else {  // MODE 4: out (L,B,E) fp32, row = l
                    ((float*)Cout)[(((size_t)row << 2) + z) * 512 + col] = v;
                }
            }
        }
    }
}

// ---------------------------------------------------------------------------
extern "C" void kernel_launch(void* const* d_in, const int* in_sizes, int n_in,
                              void* d_out, int out_size, void* d_ws,
                              size_t ws_size, hipStream_t stream) {
    const float* query = (const float*)d_in[0];
    const float* key_i = (const float*)d_in[1];
    const float* value = (const float*)d_in[2];
    const float* q_w   = (const float*)d_in[3];
    const float* q_b   = (const float*)d_in[4];
    const float* k_w   = (const float*)d_in[5];
    const float* k_b   = (const float*)d_in[6];
    const float* v_w   = (const float*)d_in[7];
    const float* v_b   = (const float*)d_in[8];

    _Float16* ws  = (_Float16*)d_ws;
    _Float16* qx  = ws;                    // 8192x512
    _Float16* kx  = qx + 4194304;
    _Float16* vx  = kx + 4194304;
    _Float16* qwf = vx + 4194304;          // 2048x512
    _Float16* kwf = qwf + 1048576;
    _Float16* vwf = kwf + 1048576;         // 512x512
    _Float16* Qb  = vwf + 262144;          // (B,L,D)
    _Float16* Kb  = Qb + 16777216;         // (B,S,D)
    _Float16* Vb  = Kb + 16777216;         // (B,S,E)
    _Float16* Vt  = Vb + 4194304;          // (B,E,S)
    _Float16* At  = Vt + 4194304;          // (B,L,S)

    // converts: one launch for the 3 activations, one for the 3 weights
    cvt3<<<dim3(2048, 3), 256, 0, stream>>>(query, key_i, value, qx, kx, vx,
                                            524288, 524288, 524288);
    cvt3<<<dim3(512, 3), 256, 0, stream>>>(q_w, k_w, v_w, qwf, kwf, vwf,
                                           131072, 131072, 32768);

    // projections
    gemm256<0><<<dim3(256), 512, 0, stream>>>(qx, qwf, q_b, Qb, 512, 0, 0, 8, 32);
    gemm256<1><<<dim3(256), 512, 0, stream>>>(kx, kwf, k_b, Kb, 512, 0, 0, 8, 32);
    gemm128p<2><<<dim3(256), 256, 0, stream>>>(vx, vwf, v_b, Vb, 512, 0, 0, 4, 64);

    transpose_v<<<dim3(16, 64, 4), 256, 0, stream>>>(Vb, Vt);

    // attn = Q K^T (batched over b)
    gemm256<3><<<dim3(256), 512, 0, stream>>>(Qb, Kb, nullptr, At, 2048,
                                              4194304, 4194304, 8, 8);

    // out = attn V
    gemm128p<4><<<dim3(256), 256, 0, stream>>>(At, Vt, nullptr, d_out, 2048,
                                               4194304, 1048576, 4, 16);
}